// Round 1
// baseline (173.073 us; speedup 1.0000x reference)
//
#include <hip/hip_runtime.h>

#define LDIM 1024
#define NSHIFT 10
#define ROW_V (LDIM / 4)            // 256 int4 per output row
#define BATCH_V (LDIM * ROW_V)      // 262144 int4 per batch = 2^18
#define NBATCH 32                   // fixed problem shape (B=32, L=1024)
#define TOTAL_V (NBATCH * BATCH_V)  // 8,388,608 int4 = 128 MiB — the LOGICAL output,
                                    // independent of out_size bytes-vs-elements convention

typedef int v4i __attribute__((ext_vector_type(4)));

// 21 band bits for row (b,i): bit (NSHIFT + d), d in [-10,10] == out[b, i, i+d].
// out[i][j] = 1 iff |i-j|<=10 and mask[k]==0 for all k in (min(i,j), max(i,j)].
__device__ __forceinline__ unsigned int band_bits(const int* __restrict__ mrow, int i)
{
    unsigned int bits = 1u << NSHIFT;   // d = 0 (diagonal) always 1
    int prod = 1;
#pragma unroll
    for (int d = 1; d <= NSHIFT; ++d) { // backward: j = i-d, need mask[(j,i]] all 0
        const int k = i - d + 1;
        const int mv = (k >= 1) ? mrow[k] : 1;   // j<0 -> force 0
        prod &= (mv == 0) ? 1 : 0;
        bits |= ((unsigned int)prod) << (NSHIFT - d);
    }
    prod = 1;
#pragma unroll
    for (int d = 1; d <= NSHIFT; ++d) { // forward: j = i+d, need mask[(i,j]] all 0
        const int k = i + d;
        const int mv = (k < LDIM) ? mrow[k] : 1; // j>1023 -> force 0
        prod &= (mv == 0) ? 1 : 0;
        bits |= ((unsigned int)prod) << (NSHIFT + d);
    }
    return bits;
}

// Single fused kernel: zero-fill + band write, exactly 128 MiB of stores.
// grid 2048 x 256 -> stride = 2^19 int4; (stride>>8)&1023 == 0 and stride%256 == 0,
// so i and j0 are invariant across grid-stride iterations (16 per thread, b += 2).
__global__ __launch_bounds__(256) void chunk_mask_fused(
    const int* __restrict__ mask, v4i* __restrict__ outv)
{
    const int stride = gridDim.x * blockDim.x;
    const int f0 = blockIdx.x * blockDim.x + threadIdx.x;
    const int i  = (f0 >> 8) & (LDIM - 1);       // output row within batch
    const int j0 = (f0 & (ROW_V - 1)) << 2;      // first int32 column of this int4

    const bool in_band = (j0 + 3 >= i - NSHIFT) && (j0 <= i + NSHIFT);

    if (!__any(in_band)) {
        // wave-uniform pure streaming fill — never re-read, bypass L2 allocate
        const v4i z = (v4i){0, 0, 0, 0};
        for (int f = f0; f < TOTAL_V; f += stride)
            __builtin_nontemporal_store(z, outv + f);
    } else {
        // ~2% of waves; i is wave-uniform, mask row is L1/L2-resident (128 KB total)
        const int base = j0 - i + NSHIFT;        // bit index for u=0
        for (int f = f0; f < TOTAL_V; f += stride) {
            const int b = f >> 18;               // batch index (f / BATCH_V)
            const unsigned int bits = band_bits(mask + b * LDIM, i);
            v4i v;
            v.x = (base     >= 0 && base     <= 2 * NSHIFT) ? (int)((bits >> (base    )) & 1u) : 0;
            v.y = (base + 1 >= 0 && base + 1 <= 2 * NSHIFT) ? (int)((bits >> (base + 1)) & 1u) : 0;
            v.z = (base + 2 >= 0 && base + 2 <= 2 * NSHIFT) ? (int)((bits >> (base + 2)) & 1u) : 0;
            v.w = (base + 3 >= 0 && base + 3 <= 2 * NSHIFT) ? (int)((bits >> (base + 3)) & 1u) : 0;
            __builtin_nontemporal_store(v, outv + f);
        }
    }
}

extern "C" void kernel_launch(void* const* d_in, const int* in_sizes, int n_in,
                              void* d_out, int out_size, void* d_ws, size_t ws_size,
                              hipStream_t stream)
{
    (void)in_sizes; (void)n_in; (void)out_size; (void)d_ws; (void)ws_size;
    const int* mask = (const int*)d_in[0];
    v4i* outv = (v4i*)d_out;

    // One kernel, one launch: exactly TOTAL_V int4 (= the logical 32x1024x1024 int32
    // output, 128 MiB) — no prepass, no workspace, no dependence on size conventions.
    chunk_mask_fused<<<2048, 256, 0, stream>>>(mask, outv);
}

// Round 2
// 165.763 us; speedup vs baseline: 1.0441x; 1.0441x over previous
//
#include <hip/hip_runtime.h>

#define LDIM 1024
#define NSHIFT 10
#define ROW_V (LDIM / 4)            // 256 int4 per output row
#define BATCH_V (LDIM * ROW_V)      // 262144 int4 per batch = 2^18
#define NBATCH 32                   // fixed problem shape (B=32, L=1024)
#define TOTAL_V (NBATCH * BATCH_V)  // 8,388,608 int4 = 128 MiB logical output

typedef int v4i __attribute__((ext_vector_type(4)));

// 21 band bits for row (b,i): bit (NSHIFT + d), d in [-10,10] == out[b, i, i+d].
// out[i][j] = 1 iff |i-j|<=10 and mask[k]==0 for all k in (min(i,j), max(i,j)].
__device__ __forceinline__ unsigned int band_bits(const int* __restrict__ mrow, int i)
{
    unsigned int bits = 1u << NSHIFT;   // d = 0 (diagonal) always 1
    int prod = 1;
#pragma unroll
    for (int d = 1; d <= NSHIFT; ++d) { // backward: j = i-d, need mask[(j,i]] all 0
        const int k = i - d + 1;
        const int mv = (k >= 1) ? mrow[k] : 1;   // j<0 -> force 0
        prod &= (mv == 0) ? 1 : 0;
        bits |= ((unsigned int)prod) << (NSHIFT - d);
    }
    prod = 1;
#pragma unroll
    for (int d = 1; d <= NSHIFT; ++d) { // forward: j = i+d, need mask[(i,j]] all 0
        const int k = i + d;
        const int mv = (k < LDIM) ? mrow[k] : 1; // j>1023 -> force 0
        prod &= (mv == 0) ? 1 : 0;
        bits |= ((unsigned int)prod) << (NSHIFT + d);
    }
    return bits;
}

// Single fused kernel: zero-fill + band write, exactly 128 MiB of PLAIN (cached)
// stores. The harness poison fill leaves the output lines L2/L3-resident; plain
// stores hit those lines at cache speed and write back lazily (measured round 0:
// plain stores sustained ~10 TB/s effective; nontemporal collapsed to 1.5 TB/s).
// grid 2048 x 256 -> stride = 2^19 int4; (stride>>8)&1023 == 0 and stride%256 == 0,
// so i and j0 are invariant across grid-stride iterations (16 per thread, b += 2).
__global__ __launch_bounds__(256) void chunk_mask_fused(
    const int* __restrict__ mask, v4i* __restrict__ outv)
{
    const int stride = gridDim.x * blockDim.x;
    const int f0 = blockIdx.x * blockDim.x + threadIdx.x;
    const int i  = (f0 >> 8) & (LDIM - 1);       // output row within batch
    const int j0 = (f0 & (ROW_V - 1)) << 2;      // first int32 column of this int4

    const bool in_band = (j0 + 3 >= i - NSHIFT) && (j0 <= i + NSHIFT);

    if (!__any(in_band)) {
        // wave-uniform pure streaming fill path
        const v4i z = (v4i){0, 0, 0, 0};
        for (int f = f0; f < TOTAL_V; f += stride)
            outv[f] = z;
    } else {
        // ~2% of waves; i is wave-uniform, mask rows are L1/L2-resident (128 KB total)
        const int base = j0 - i + NSHIFT;        // bit index for u=0
        for (int f = f0; f < TOTAL_V; f += stride) {
            const int b = f >> 18;               // batch index (f / BATCH_V)
            const unsigned int bits = band_bits(mask + b * LDIM, i);
            v4i v;
            v.x = (base     >= 0 && base     <= 2 * NSHIFT) ? (int)((bits >> (base    )) & 1u) : 0;
            v.y = (base + 1 >= 0 && base + 1 <= 2 * NSHIFT) ? (int)((bits >> (base + 1)) & 1u) : 0;
            v.z = (base + 2 >= 0 && base + 2 <= 2 * NSHIFT) ? (int)((bits >> (base + 2)) & 1u) : 0;
            v.w = (base + 3 >= 0 && base + 3 <= 2 * NSHIFT) ? (int)((bits >> (base + 3)) & 1u) : 0;
            outv[f] = v;
        }
    }
}

extern "C" void kernel_launch(void* const* d_in, const int* in_sizes, int n_in,
                              void* d_out, int out_size, void* d_ws, size_t ws_size,
                              hipStream_t stream)
{
    (void)in_sizes; (void)n_in; (void)out_size; (void)d_ws; (void)ws_size;
    const int* mask = (const int*)d_in[0];
    v4i* outv = (v4i*)d_out;

    // One kernel, one launch: exactly TOTAL_V int4 (= the logical 32x1024x1024 int32
    // output, 128 MiB). Plain cached stores — see comment above.
    chunk_mask_fused<<<2048, 256, 0, stream>>>(mask, outv);
}

// Round 3
// 137.786 us; speedup vs baseline: 1.2561x; 1.2030x over previous
//
#include <hip/hip_runtime.h>

#define LDIM 1024
#define NSHIFT 10
#define ROW_V (LDIM / 4)            // 256 int4 per output row
#define BATCH_V (LDIM * ROW_V)      // 262144 int4 per batch = 2^18
#define NBATCH 32                   // fixed problem shape (B=32, L=1024)
#define TOTAL_V (NBATCH * BATCH_V)  // 8,388,608 int4 = 128 MiB logical output

typedef int v4i __attribute__((ext_vector_type(4)));

// Pre-pass: for each (b,i) compute 21 band bits.
// bit (NSHIFT + d), d in [-10,10]:  out[b, i, i+d]
// Band waves in the fill then need only ONE broadcast load per iteration —
// round 2 proved inlining these 20 loads into the fill serializes the band
// waves on L2 latency (~60 us critical path).
__global__ __launch_bounds__(256) void band_prepass(
    const int* __restrict__ mask, unsigned int* __restrict__ bandtab, int n)
{
    const int idx = blockIdx.x * blockDim.x + threadIdx.x;  // (b<<10)|i
    if (idx >= n) return;
    const int b = idx >> 10;
    const int i = idx & (LDIM - 1);
    const int* __restrict__ mrow = mask + b * LDIM;

    unsigned int bits = 1u << NSHIFT;   // d = 0 (diagonal) always 1
    int prod = 1;
#pragma unroll
    for (int d = 1; d <= NSHIFT; ++d) { // backward: j = i-d, need mask[(j,i]] all 0
        const int k = i - d + 1;
        const int mv = (k >= 1) ? mrow[k] : 1;   // j<0 -> force 0
        prod &= (mv == 0) ? 1 : 0;
        bits |= ((unsigned int)prod) << (NSHIFT - d);
    }
    prod = 1;
#pragma unroll
    for (int d = 1; d <= NSHIFT; ++d) { // forward: j = i+d, need mask[(i,j]] all 0
        const int k = i + d;
        const int mv = (k < LDIM) ? mrow[k] : 1; // j>1023 -> force 0
        prod &= (mv == 0) ? 1 : 0;
        bits |= ((unsigned int)prod) << (NSHIFT + d);
    }
    bandtab[idx] = bits;
}

// Fill: exactly the logical 128 MiB output, plain cached stores.
// grid 2048 x 256 -> stride = 2^19 int4; (stride>>8)&1023 == 0 and stride%256 == 0,
// so i and j0 are invariant across grid-stride iterations (16 per thread, b += 2).
__global__ __launch_bounds__(256) void chunk_mask_fill(
    const unsigned int* __restrict__ bandtab, v4i* __restrict__ outv)
{
    const int stride = gridDim.x * blockDim.x;
    const int f0 = blockIdx.x * blockDim.x + threadIdx.x;
    const int i  = (f0 >> 8) & (LDIM - 1);       // output row within batch
    const int j0 = (f0 & (ROW_V - 1)) << 2;      // first int32 column of this int4

    const bool in_band = (j0 + 3 >= i - NSHIFT) && (j0 <= i + NSHIFT);

    if (!__any(in_band)) {
        // wave-uniform pure streaming fill path
        const v4i z = (v4i){0, 0, 0, 0};
        for (int f = f0; f < TOTAL_V; f += stride)
            outv[f] = z;
    } else {
        // band waves: ONE broadcast dword load per iteration (L2-hot, 128 KB table)
        const int base = j0 - i + NSHIFT;        // bit index for u=0
        for (int f = f0; f < TOTAL_V; f += stride) {
            const int b = f >> 18;               // batch index (f / BATCH_V)
            const unsigned int bits = bandtab[(b << 10) | i];
            v4i v;
            v.x = (base     >= 0 && base     <= 2 * NSHIFT) ? (int)((bits >> (base    )) & 1u) : 0;
            v.y = (base + 1 >= 0 && base + 1 <= 2 * NSHIFT) ? (int)((bits >> (base + 1)) & 1u) : 0;
            v.z = (base + 2 >= 0 && base + 2 <= 2 * NSHIFT) ? (int)((bits >> (base + 2)) & 1u) : 0;
            v.w = (base + 3 >= 0 && base + 3 <= 2 * NSHIFT) ? (int)((bits >> (base + 3)) & 1u) : 0;
            outv[f] = v;
        }
    }
}

extern "C" void kernel_launch(void* const* d_in, const int* in_sizes, int n_in,
                              void* d_out, int out_size, void* d_ws, size_t ws_size,
                              hipStream_t stream)
{
    (void)n_in; (void)out_size; (void)ws_size;
    const int* mask = (const int*)d_in[0];
    v4i* outv = (v4i*)d_out;
    unsigned int* bandtab = (unsigned int*)d_ws;   // 128 KB used

    const int B = in_sizes[0] / LDIM;              // 32
    const int n_rows = B * LDIM;                   // 32768

    band_prepass<<<(n_rows + 255) / 256, 256, 0, stream>>>(mask, bandtab, n_rows);
    chunk_mask_fill<<<2048, 256, 0, stream>>>(bandtab, outv);
}